// Round 1
// baseline (805.514 us; speedup 1.0000x reference)
//
#include <hip/hip_runtime.h>
#include <math.h>

#define N_LEVELS 16
#define LOG2_T 19
#define TABLE_SIZE (1 << LOG2_T)

struct ResTable { float r[N_LEVELS]; };

// One thread per (point, level). level = tid & 15, n = tid >> 4.
// Output (N, 16, 2) fp32: thread writes float2 at out + tid*2 -> fully coalesced.
__global__ __launch_bounds__(256) void ingp_hash_kernel(
    const float* __restrict__ x,
    const float* __restrict__ emb,
    float* __restrict__ out,
    int n_pts,
    ResTable res)
{
    int t = blockIdx.x * blockDim.x + threadIdx.x;
    int level = t & (N_LEVELS - 1);
    int n = t >> 4;
    if (n >= n_pts) return;

    // clip to [-1, 1]
    float xx = fminf(fmaxf(x[n * 3 + 0], -1.0f), 1.0f);
    float xy = fminf(fmaxf(x[n * 3 + 1], -1.0f), 1.0f);
    float xz = fminf(fmaxf(x[n * 3 + 2], -1.0f), 1.0f);

    float r = res.r[level];
    float grid = 2.0f / r;  // (BOX_MAX - BOX_MIN) / res, fp32 IEEE div == numpy

    // bottom-left voxel index: floor((x - BOX_MIN) / grid)  — integer path must
    // be bit-exact vs numpy fp32: add, div, floor only (no contractable FMA).
    float tx = (xx + 1.0f) / grid;
    float ty = (xy + 1.0f) / grid;
    float tz = (xz + 1.0f) / grid;
    int blx = (int)floorf(tx);
    int bly = (int)floorf(ty);
    int blz = (int)floorf(tz);

    // trilinear weights w = (x - vmin) / grid, vmin = bl*grid + BOX_MIN
    float wx = (xx - ((float)blx * grid + -1.0f)) / grid;
    float wy = (xy - ((float)bly * grid + -1.0f)) / grid;
    float wz = (xz - ((float)blz * grid + -1.0f)) / grid;

    const float* __restrict__ table = emb + (size_t)level * (TABLE_SIZE * 2);

    float acc0 = 0.0f, acc1 = 0.0f;
#pragma unroll
    for (int k = 0; k < 8; ++k) {
        // OFFSETS bit order: x = k>>2, y = k>>1, z = k  (matches reference table)
        int bx = (k >> 2) & 1;
        int by = (k >> 1) & 1;
        int bz = k & 1;
        unsigned cx = (unsigned)(blx + bx);
        unsigned cy = (unsigned)(bly + by);
        unsigned cz = (unsigned)(blz + bz);
        // h = cx*1 ^ cy*2654435761 ^ cz*805459861  (uint32 wrap)
        unsigned h = cx ^ (cy * 2654435761u) ^ (cz * 805459861u);
        unsigned idx = h & (unsigned)(TABLE_SIZE - 1);
        float2 e = *(const float2*)(table + (size_t)idx * 2);
        float fx = bx ? wx : 1.0f - wx;
        float fy = by ? wy : 1.0f - wy;
        float fz = bz ? wz : 1.0f - wz;
        float wgt = (fx * fy) * fz;
        acc0 += wgt * e.x;
        acc1 += wgt * e.y;
    }

    float2* o = (float2*)out;
    o[t] = make_float2(acc0, acc1);
}

extern "C" void kernel_launch(void* const* d_in, const int* in_sizes, int n_in,
                              void* d_out, int out_size, void* d_ws, size_t ws_size,
                              hipStream_t stream) {
    const float* x   = (const float*)d_in[0];
    const float* emb = (const float*)d_in[1];
    float* out = (float*)d_out;
    int n_pts = in_sizes[0] / 3;

    // RESOLUTIONS: replicate numpy float64 semantics on host (same libm as np):
    // b = exp((log(512) - log(16)) / 15); res_i = float32(floor(16 * b**i))
    ResTable res;
    double b = exp((log(512.0) - log(16.0)) / 15.0);
    for (int i = 0; i < N_LEVELS; ++i) {
        res.r[i] = (float)floor(16.0 * pow(b, (double)i));
    }

    int total = n_pts * N_LEVELS;
    int threads = 256;
    int blocks = (total + threads - 1) / threads;
    hipLaunchKernelGGL(ingp_hash_kernel, dim3(blocks), dim3(threads), 0, stream,
                       x, emb, out, n_pts, res);
}